// Round 7
// baseline (240.226 us; speedup 1.0000x reference)
//
#include <hip/hip_runtime.h>
#include <math.h>

#define Bdim 2
#define Sdim 2048
#define Ddim 1024
#define Hnum 16
#define HDdim 64
#define Kdim 1024

using short8   = __attribute__((ext_vector_type(8))) short;
using ushort8  = __attribute__((ext_vector_type(8))) unsigned short;
using ushort4v = __attribute__((ext_vector_type(4))) unsigned short;
using floatx4  = __attribute__((ext_vector_type(4))) float;
using half4    = __attribute__((ext_vector_type(4))) _Float16;
using half2v   = __attribute__((ext_vector_type(2))) _Float16;

__device__ __forceinline__ unsigned short f2bf(float f) {
    __bf16 b = (__bf16)f;
    return __builtin_bit_cast(unsigned short, b);
}

// async global->LDS, 16B per lane. LDS dest is wave-uniform base + lane*16.
__device__ __forceinline__ void async_ld16(const unsigned short* g, unsigned short* l) {
    __builtin_amdgcn_global_load_lds(
        (const __attribute__((address_space(1))) unsigned int*)(g),
        (__attribute__((address_space(3))) unsigned int*)(l), 16, 0, 0);
}

// ---------------------------------------------------------------------------
// Prep (shrunk): [0,2048) x fp32->bf16; [2048,3072) W transpose->bf16 [n][k].
// Mask packing moved into qkv kernel (pmk needed only by attn -> overlaps
// with qkv GEMM instead of serializing before it).
// ---------------------------------------------------------------------------
__global__ __launch_bounds__(256) void prep_kernel(
    const float* __restrict__ x,
    const float* __restrict__ Wq, const float* __restrict__ Wk,
    const float* __restrict__ Wv, const float* __restrict__ Wo,
    unsigned short* __restrict__ xb, unsigned short* __restrict__ Wt)
{
    __shared__ float tile[64][65];
    const int bid = blockIdx.x;
    const int t   = threadIdx.x;

    if (bid < 2048) {
        // ---- x -> bf16 ----
        size_t i = ((size_t)bid * 256 + t) * 8;
        float4 a = *(const float4*)(x + i);
        float4 b = *(const float4*)(x + i + 4);
        ushort8 o;
        o[0] = f2bf(a.x); o[1] = f2bf(a.y); o[2] = f2bf(a.z); o[3] = f2bf(a.w);
        o[4] = f2bf(b.x); o[5] = f2bf(b.y); o[6] = f2bf(b.z); o[7] = f2bf(b.w);
        *(ushort8*)(xb + i) = o;
    } else {
        // ---- W [k][n] -> Wt [z][n][k] bf16, 64x64 tiles ----
        const int idx = bid - 2048;
        const int n0 = (idx & 15) * 64;
        const int k0 = ((idx >> 4) & 15) * 64;
        const int z  = idx >> 8;
        const float* W = (z == 0) ? Wq : (z == 1) ? Wk : (z == 2) ? Wv : Wo;
        unsigned short* outp = Wt + (size_t)z * Kdim * Ddim;
#pragma unroll
        for (int i = 0; i < 4; ++i) {
            int flat = i * 256 + t;
            int r = flat >> 4;
            int c = (flat & 15) * 4;
            float4 v = *(const float4*)(W + (size_t)(k0 + r) * Ddim + n0 + c);
            tile[r][c] = v.x; tile[r][c+1] = v.y; tile[r][c+2] = v.z; tile[r][c+3] = v.w;
        }
        __syncthreads();
#pragma unroll
        for (int i = 0; i < 16; ++i) {
            int flat = i * 256 + t;
            int n = flat >> 6;
            int k = flat & 63;
            outp[(size_t)(n0 + n) * Kdim + k0 + k] = f2bf(tile[k][n]);
        }
    }
}

// ---------------------------------------------------------------------------
// bf16 MFMA GEMM K-loop (m97 structure), 128 x BN tile, BK=64.
// MFMA_NORM: C (lane=n-col, regs=m-rows).  MFMA_SWAP: C^T (lane=m, regs=n).
// ---------------------------------------------------------------------------
#define MFMA_NORM(MT, NT) acc[MT][NT] = __builtin_amdgcn_mfma_f32_16x16x32_bf16(af[MT], bfr[NT], acc[MT][NT], 0, 0, 0)
#define MFMA_SWAP(MT, NT) acc[MT][NT] = __builtin_amdgcn_mfma_f32_16x16x32_bf16(bfr[NT], af[MT], acc[MT][NT], 0, 0, 0)

#define GEMM_KLOOP(APTR, WPTR, NT_TILES, MFMA_STMT)                              \
    for (int kt = 0; kt < 16; ++kt) {                                            \
        const int k0 = kt * 64;                                                  \
        __syncthreads();                                                         \
        _Pragma("unroll")                                                        \
        for (int i = 0; i < 4; ++i) {                                            \
            int flat = i * 256 + t;                                              \
            int row  = flat >> 3;                                                \
            int cg   = (flat & 7) ^ (row & 7);                                   \
            async_ld16(APTR + (size_t)(m0 + row) * Kdim + k0 + cg * 8,           \
                       As + flat * 8);                                           \
        }                                                                        \
        _Pragma("unroll")                                                        \
        for (int i = 0; i < NT_TILES; ++i) {                                     \
            int flat = i * 256 + t;                                              \
            int row  = flat >> 3;                                                \
            int cg   = (flat & 7) ^ (row & 7);                                   \
            async_ld16(WPTR + (size_t)row * Kdim + k0 + cg * 8,                  \
                       Bs + flat * 8);                                           \
        }                                                                        \
        __syncthreads();                                                         \
        _Pragma("unroll")                                                        \
        for (int ks = 0; ks < 2; ++ks) {                                         \
            short8 af[4], bfr[NT_TILES];                                         \
            _Pragma("unroll")                                                    \
            for (int mt = 0; mt < 4; ++mt) {                                     \
                int row = wm * 64 + mt * 16 + l15;                               \
                int ch  = (ks * 4 + quad) ^ (row & 7);                           \
                af[mt] = *(const short8*)(As + row * 64 + ch * 8);               \
            }                                                                    \
            _Pragma("unroll")                                                    \
            for (int nt = 0; nt < NT_TILES; ++nt) {                              \
                int row = wn * (NT_TILES * 16) + nt * 16 + l15;                  \
                int ch  = (ks * 4 + quad) ^ (row & 7);                           \
                bfr[nt] = *(const short8*)(Bs + row * 64 + ch * 8);              \
            }                                                                    \
            _Pragma("unroll")                                                    \
            for (int mt = 0; mt < 4; ++mt)                                       \
                _Pragma("unroll")                                                \
                for (int nt = 0; nt < NT_TILES; ++nt)                            \
                    MFMA_STMT(mt, nt);                                           \
        }                                                                        \
    }

// ---------------------------------------------------------------------------
// Fused QKV projection + mask packing. Blocks [0,768): GEMM with XCD-chunked
// swizzle (each XCD owns a 12x8 rectangle). Blocks [768,8960): mask int32 ->
// per-wave lane-mask words (pmk, consumed only by attn) -- runs in the GEMM
// blocks' retirement shadow instead of serializing in prep.
// ---------------------------------------------------------------------------
__global__ __launch_bounds__(256) void qkv_mfma_kernel(
    const unsigned short* __restrict__ A, const unsigned short* __restrict__ Wt,
    const float* __restrict__ bq, const float* __restrict__ bk, const float* __restrict__ bv,
    unsigned short* __restrict__ qo, unsigned short* __restrict__ ko, _Float16* __restrict__ vto,
    const int* __restrict__ mask, unsigned long long* __restrict__ packed)
{
    __shared__ __align__(16) unsigned short As[128 * 64];
    __shared__ __align__(16) unsigned short Bs[128 * 64];
    const int bid = blockIdx.x;
    const int t   = threadIdx.x;

    if (bid >= 768) {
        // ---- mask pack: wave group gid=(b,qg,kb); lane (l15,quad) reads int4,
        //      4 ballots give words [gid*4 + r] ----
        const int lane = t & 63;
        const int l15  = lane & 15;
        const int quad = lane >> 4;
        const unsigned int gid = (bid - 768) * 4 + (t >> 6);
        const int b  = gid >> 14;
        const int qg = (gid >> 7) & 127;
        const int kb = gid & 127;
        int4 mv = *(const int4*)(mask + ((size_t)(b * Sdim) + qg * 16 + l15) * Sdim + kb * 16 + quad * 4);
        unsigned long long w0 = __ballot(mv.x != 0);
        unsigned long long w1 = __ballot(mv.y != 0);
        unsigned long long w2 = __ballot(mv.z != 0);
        unsigned long long w3 = __ballot(mv.w != 0);
        if (lane == 0) {
            unsigned long long* dst = packed + (size_t)gid * 4;
            dst[0] = w0; dst[1] = w1; dst[2] = w2; dst[3] = w3;
        }
        return;
    }

    // XCD swizzle (dispatch round-robins linear bid % 8): lin -> (bx,by)
    const int lin = bid;
    const int xcd = lin & 7;
    const int idx = lin >> 3;                 // 0..95
    const int bx  = (xcd & 1) * 12 + idx % 12;
    const int by  = (xcd >> 1) * 8 + idx / 12;
    const int n0   = bx * 128;
    const int m0   = by * 128;
    const int wsel = n0 >> 10;
    const int c0   = n0 & 1023;
    const unsigned short* Wp = Wt + (size_t)wsel * Kdim * Ddim + (size_t)c0 * Kdim;

    const int lane = t & 63;
    const int w    = t >> 6;
    const int quad = lane >> 4;
    const int l15  = lane & 15;
    const int wm   = w & 1;
    const int wn   = w >> 1;
    floatx4 acc[4][4];
#pragma unroll
    for (int mt = 0; mt < 4; ++mt)
#pragma unroll
        for (int nt = 0; nt < 4; ++nt) acc[mt][nt] = (floatx4){0.f, 0.f, 0.f, 0.f};

    if (wsel < 2) {
        GEMM_KLOOP(A, Wp, 4, MFMA_SWAP)
        const float* bias = wsel ? bk : bq;
        unsigned short* outp = wsel ? ko : qo;
        const float qsc = wsel ? 1.0f : 0.18033688011112042f;  // q: 0.125*log2(e)
#pragma unroll
        for (int mt = 0; mt < 4; ++mt) {
            int m    = m0 + wm * 64 + mt * 16 + l15;  // s-row
            int bidx = m >> 11;
            int s    = m & 2047;
#pragma unroll
            for (int nt = 0; nt < 4; ++nt) {
                int c = c0 + wn * 64 + nt * 16 + quad * 4;  // 4 contiguous cols
                float4 bb = *(const float4*)(bias + c);
                int h  = c >> 6;
                int hd = c & 63;
                ushort4v o;
                o[0] = f2bf((acc[mt][nt][0] + bb.x) * qsc);
                o[1] = f2bf((acc[mt][nt][1] + bb.y) * qsc);
                o[2] = f2bf((acc[mt][nt][2] + bb.z) * qsc);
                o[3] = f2bf((acc[mt][nt][3] + bb.w) * qsc);
                *(ushort4v*)(outp + ((size_t)(bidx * Hnum + h) * Sdim + s) * HDdim + hd) = o;
            }
        }
    } else {
        GEMM_KLOOP(A, Wp, 4, MFMA_NORM)
#pragma unroll
        for (int nt = 0; nt < 4; ++nt) {
            int c = c0 + wn * 64 + nt * 16 + l15;
            float bb = bv[c];
            int h  = c >> 6;
            int hd = c & 63;
#pragma unroll
            for (int mt = 0; mt < 4; ++mt) {
                int m    = m0 + wm * 64 + mt * 16 + quad * 4;  // 4 contiguous s
                int bidx = m >> 11;
                int s    = m & 2047;
                half4 o;
#pragma unroll
                for (int r = 0; r < 4; ++r) o[r] = (_Float16)(acc[mt][nt][r] + bb);
                *(half4*)(vto + ((size_t)(bidx * Hnum + h) * HDdim + hd) * Sdim + s) = o;
            }
        }
    }
}

// ---------------------------------------------------------------------------
// Output projection (operand-swapped), 128x64 tiles: grid 512 blocks (2/CU).
// fp32 out + bias, float4 coalesced stores. XCD swizzle: each XCD owns 4
// consecutive y (A-panels) x all x.
// ---------------------------------------------------------------------------
__global__ __launch_bounds__(256) void out_mfma_kernel(
    const unsigned short* __restrict__ A, const unsigned short* __restrict__ Wt,
    const float* __restrict__ bias, float* __restrict__ out)
{
    __shared__ __align__(16) unsigned short As[128 * 64];
    __shared__ __align__(16) unsigned short Bs[64 * 64];
    const int lin = blockIdx.y * 16 + blockIdx.x;
    const int xcd = lin & 7;
    const int idx = lin >> 3;                 // 0..63
    const int bx  = idx & 15;
    const int by  = xcd * 4 + (idx >> 4);
    const int n0 = bx * 64;
    const int m0 = by * 128;
    const unsigned short* Wp = Wt + (size_t)3 * Kdim * Ddim + (size_t)n0 * Kdim;

    const int t    = threadIdx.x;
    const int lane = t & 63;
    const int w    = t >> 6;
    const int quad = lane >> 4;
    const int l15  = lane & 15;
    const int wm   = w & 1;
    const int wn   = w >> 1;
    floatx4 acc[4][2];
#pragma unroll
    for (int mt = 0; mt < 4; ++mt)
#pragma unroll
        for (int nt = 0; nt < 2; ++nt) acc[mt][nt] = (floatx4){0.f, 0.f, 0.f, 0.f};

    GEMM_KLOOP(A, Wp, 2, MFMA_SWAP)

#pragma unroll
    for (int mt = 0; mt < 4; ++mt) {
        int m = m0 + wm * 64 + mt * 16 + l15;  // s-row
#pragma unroll
        for (int nt = 0; nt < 2; ++nt) {
            int c = n0 + wn * 32 + nt * 16 + quad * 4;
            float4 bb = *(const float4*)(bias + c);
            float4 o = make_float4(acc[mt][nt][0] + bb.x, acc[mt][nt][1] + bb.y,
                                   acc[mt][nt][2] + bb.z, acc[mt][nt][3] + bb.w);
            *(float4*)(out + (size_t)m * Ddim + c) = o;
        }
    }
}

// ---------------------------------------------------------------------------
// MFMA flash attention v9 (unchanged, best measured 75.9us): v6b 2x2 wave
// decomposition + T5 s_setprio around QK/PV MFMA clusters. Wave (wq,wk) owns
// 32 q-rows x 32 keys; grid 1024 (4 blocks/CU). Same-bh blocks 32 apart ==
// same XCD under round-robin: KV L2-clustered.
// ---------------------------------------------------------------------------
__global__ __launch_bounds__(256, 4) void attn_mfma_kernel(
    const unsigned short* __restrict__ q, const unsigned short* __restrict__ k,
    const _Float16* __restrict__ vt, const unsigned long long* __restrict__ pmask,
    unsigned short* __restrict__ ctx)
{
    __shared__ __align__(16) unsigned short Ks[2][64 * 64];  // [key][hd], swizzled
    __shared__ __align__(16) _Float16       Vs[2][64 * 64];  // [hd][key], swizzled

    const int t    = threadIdx.x;
    const int w    = t >> 6;
    const int lane = t & 63;
    const int quad = lane >> 4;
    const int l15  = lane & 15;
    const int bid  = blockIdx.x;
    const int bh   = bid & 31;
    const int qseg = bid >> 5;          // 0..31
    const int b    = bh >> 4;
    const int h    = bh & 15;
    const int wq   = w & 1;             // q-half of the block's 64 rows
    const int wk   = w >> 1;            // key-half of each 64-key tile
    const int qrow0 = qseg * 64 + wq * 32;   // 32 q-rows per wave (g=0,1)

    const unsigned short* qp = q  + (size_t)bh * Sdim * HDdim;
    const unsigned short* kp = k  + (size_t)bh * Sdim * HDdim;
    const _Float16*       vp = vt + (size_t)bh * HDdim * Sdim;

    // wave-uniform mask base (scalar loads feed v_cndmask's "s" operand)
    const int qg0 = __builtin_amdgcn_readfirstlane(qrow0 >> 4);
    const int wku = __builtin_amdgcn_readfirstlane(wk);
    const unsigned long long* __restrict__ pm =
        pmask + ((size_t)(b * 128 + qg0) * 128) * 4 + wku * 8;

    short8 qf[2][2];
#pragma unroll
    for (int g = 0; g < 2; ++g)
#pragma unroll
        for (int ks = 0; ks < 2; ++ks)
            qf[g][ks] = *(const short8*)(qp + (size_t)(qrow0 + g * 16 + l15) * HDdim + ks * 32 + quad * 8);

    floatx4 acc[2][4];
    floatx4 accl[2];
#pragma unroll
    for (int g = 0; g < 2; ++g) {
        accl[g] = (floatx4){0.f, 0.f, 0.f, 0.f};
#pragma unroll
        for (int hs = 0; hs < 4; ++hs) acc[g][hs] = (floatx4){0.f, 0.f, 0.f, 0.f};
    }
    const half4 ones = {(_Float16)1.f, (_Float16)1.f, (_Float16)1.f, (_Float16)1.f};

    // stage key-tile into buf: 256 threads x (2 K + 2 V) DMA insts.
    auto stage = [&](int buf, int key0) {
#pragma unroll
        for (int i = 0; i < 2; ++i) {
            int flat = i * 256 + t;
            int row  = flat >> 3;
            int cg   = (flat & 7) ^ (row & 7);
            async_ld16(kp + (size_t)(key0 + row) * HDdim + cg * 8, &Ks[buf][flat * 8]);
        }
#pragma unroll
        for (int i = 0; i < 2; ++i) {
            int flat = i * 256 + t;
            int row  = flat >> 3;
            int cg   = (flat & 7) ^ (row & 7);
            async_ld16((const unsigned short*)(vp + (size_t)row * Sdim + key0 + cg * 8),
                       (unsigned short*)&Vs[buf][flat * 8]);
        }
    };

    stage(0, 0);

#pragma unroll 2
    for (int kt = 0; kt < 32; ++kt) {
        const int cur = kt & 1;
        __syncthreads();
        if (kt < 31) stage(cur ^ 1, (kt + 1) * 64);

        // wave's key-half of K: rows [wk*32, wk*32+32)
        short8 kf[2][2];
#pragma unroll
        for (int ks = 0; ks < 2; ++ks)
#pragma unroll
            for (int sub = 0; sub < 2; ++sub) {
                int row = wk * 32 + sub * 16 + l15;
                int ch  = (ks * 4 + quad) ^ (row & 7);
                kf[ks][sub] = *(const short8*)&Ks[cur][row * 64 + ch * 8];
            }
        // wave's key-half of V: key cols [wk*32, wk*32+32)
        half4 vf[4][2];
#pragma unroll
        for (int hs = 0; hs < 4; ++hs)
#pragma unroll
            for (int c = 0; c < 2; ++c) {
                int row = hs * 16 + l15;
                int cc  = (wk * 2 + c) * 2 + (quad >> 1);
                int ch  = cc ^ (row & 7);
                vf[hs][c] = *(const half4*)&Vs[cur][row * 64 + ch * 8 + (quad & 1) * 4];
            }

        floatx4 sc[2][2];
#pragma unroll
        for (int g = 0; g < 2; ++g)
#pragma unroll
            for (int sub = 0; sub < 2; ++sub) sc[g][sub] = (floatx4){0.f, 0.f, 0.f, 0.f};
        __builtin_amdgcn_s_setprio(1);
#pragma unroll
        for (int ks = 0; ks < 2; ++ks)
#pragma unroll
            for (int sub = 0; sub < 2; ++sub)
#pragma unroll
                for (int g = 0; g < 2; ++g)
                    sc[g][sub] = __builtin_amdgcn_mfma_f32_16x16x32_bf16(
                        kf[ks][sub], qf[g][ks], sc[g][sub], 0, 0, 0);
        __builtin_amdgcn_s_setprio(0);

        // sc[g][sub][r] = score[q=qrow0+g*16+l15][key = kt*64 + wk*32 + sub*16 + quad*4 + r]
        half4 pf[2][2];
#pragma unroll
        for (int g = 0; g < 2; ++g) {
            const unsigned long long* __restrict__ pg = pm + g * 512 + kt * 16;
#pragma unroll
            for (int c = 0; c < 2; ++c) {
                float pv[4];
#pragma unroll
                for (int r = 0; r < 4; ++r) {
                    float p = exp2f(sc[g][c][r]);
                    unsigned long long wmask = pg[c * 4 + r];
                    asm("v_cndmask_b32 %0, 0, %1, %2" : "=v"(pv[r]) : "v"(p), "s"(wmask));
                }
                half2v lo = __builtin_bit_cast(half2v, __builtin_amdgcn_cvt_pkrtz(pv[0], pv[1]));
                half2v hi = __builtin_bit_cast(half2v, __builtin_amdgcn_cvt_pkrtz(pv[2], pv[3]));
                pf[g][c][0] = lo[0]; pf[g][c][1] = lo[1];
                pf[g][c][2] = hi[0]; pf[g][c][3] = hi[1];
            }
        }

        __builtin_amdgcn_s_setprio(1);
#pragma unroll
        for (int c = 0; c < 2; ++c) {
#pragma unroll
            for (int hs = 0; hs < 4; ++hs)
#pragma unroll
                for (int g = 0; g < 2; ++g)
                    acc[g][hs] = __builtin_amdgcn_mfma_f32_16x16x16f16(
                        vf[hs][c], pf[g][c], acc[g][hs], 0, 0, 0);
#pragma unroll
            for (int g = 0; g < 2; ++g)
                accl[g] = __builtin_amdgcn_mfma_f32_16x16x16f16(
                    ones, pf[g][c], accl[g], 0, 0, 0);
        }
        __builtin_amdgcn_s_setprio(0);
    }

    // ---- cross-wave (wk) reduction of partial ctx / l through dead LDS ----
    __syncthreads();
    float* red  = (float*)&Ks[0][0];   // 16 slots x 64 lanes x floatx4 = 16KB
    float* redl = (float*)&Vs[0][0];   // 4 slots x 64 lanes x f32 = 1KB
    if (wk == 1) {
#pragma unroll
        for (int g = 0; g < 2; ++g) {
#pragma unroll
            for (int hs = 0; hs < 4; ++hs)
                *(floatx4*)&red[((((wq * 2) + g) * 4 + hs) * 64 + lane) * 4] = acc[g][hs];
            redl[(wq * 2 + g) * 64 + lane] = accl[g][0];
        }
    }
    __syncthreads();
    if (wk == 0) {
#pragma unroll
        for (int g = 0; g < 2; ++g) {
            float lsum = accl[g][0] + redl[(wq * 2 + g) * 64 + lane];
            float inv  = 1.0f / fmaxf(lsum, 1e-30f);
            int row = qrow0 + g * 16 + l15;
#pragma unroll
            for (int hs = 0; hs < 4; ++hs) {
                floatx4 o4 = acc[g][hs] + *(const floatx4*)&red[((((wq * 2) + g) * 4 + hs) * 64 + lane) * 4];
                ushort4v o;
#pragma unroll
                for (int r = 0; r < 4; ++r) o[r] = f2bf(o4[r] * inv);
                *(ushort4v*)(ctx + (size_t)(b * Sdim + row) * Ddim + h * 64 + hs * 16 + quad * 4) = o;
            }
        }
    }
}

// ---------------------------------------------------------------------------
extern "C" void kernel_launch(void* const* d_in, const int* in_sizes, int n_in,
                              void* d_out, int out_size, void* d_ws, size_t ws_size,
                              hipStream_t stream) {
    const float* x   = (const float*)d_in[0];
    const float* Wq  = (const float*)d_in[1];
    const float* bq  = (const float*)d_in[2];
    const float* Wk  = (const float*)d_in[3];
    const float* bk  = (const float*)d_in[4];
    const float* Wv  = (const float*)d_in[5];
    const float* bv  = (const float*)d_in[6];
    const float* Wo  = (const float*)d_in[7];
    const float* bo  = (const float*)d_in[8];
    // d_in[9] cross_modal_weights: softmax-shift-invariant -> unused
    const int*  mask = (const int*)d_in[10];
    // d_in[11] modality_info: unused by the reference
    float* out = (float*)d_out;

    char* ws = (char*)d_ws;
    unsigned short* xb  = (unsigned short*)(ws);                         // 8 MB
    unsigned short* Wt  = (unsigned short*)(ws + (size_t)8  * 1048576);  // 8 MB
    unsigned short* qb  = (unsigned short*)(ws + (size_t)16 * 1048576);  // 8 MB
    unsigned short* kb  = (unsigned short*)(ws + (size_t)24 * 1048576);  // 8 MB
    _Float16*       vtb = (_Float16*)     (ws + (size_t)32 * 1048576);   // 8 MB f16 [bh][hd][s]
    unsigned long long* pmk = (unsigned long long*)(ws + (size_t)40 * 1048576); // 1 MB
    unsigned short* ctxb = xb;  // alias: xb consumed before attn writes ctx

    prep_kernel<<<dim3(3072), 256, 0, stream>>>(x, Wq, Wk, Wv, Wo, xb, Wt);
    qkv_mfma_kernel<<<dim3(8960), 256, 0, stream>>>(xb, Wt, bq, bk, bv, qb, kb, vtb, mask, pmk);
    attn_mfma_kernel<<<dim3(1024), 256, 0, stream>>>(qb, kb, vtb, pmk, ctxb);
    out_mfma_kernel<<<dim3(16, 32), 256, 0, stream>>>(ctxb, Wt, bo, out);
}

// Round 9
// 232.103 us; speedup vs baseline: 1.0350x; 1.0350x over previous
//
#include <hip/hip_runtime.h>
#include <math.h>

#define Bdim 2
#define Sdim 2048
#define Ddim 1024
#define Hnum 16
#define HDdim 64
#define Kdim 1024

using short8   = __attribute__((ext_vector_type(8))) short;
using ushort8  = __attribute__((ext_vector_type(8))) unsigned short;
using ushort4v = __attribute__((ext_vector_type(4))) unsigned short;
using floatx4  = __attribute__((ext_vector_type(4))) float;
using half4    = __attribute__((ext_vector_type(4))) _Float16;
using half2v   = __attribute__((ext_vector_type(2))) _Float16;

__device__ __forceinline__ unsigned short f2bf(float f) {
    __bf16 b = (__bf16)f;
    return __builtin_bit_cast(unsigned short, b);
}

// async global->LDS, 16B per lane. LDS dest is wave-uniform base + lane*16.
__device__ __forceinline__ void async_ld16(const unsigned short* g, unsigned short* l) {
    __builtin_amdgcn_global_load_lds(
        (const __attribute__((address_space(1))) unsigned int*)(g),
        (__attribute__((address_space(3))) unsigned int*)(l), 16, 0, 0);
}

// ---------------------------------------------------------------------------
// Fused prep: [0,2048) x fp32->bf16; [2048,3072) W transpose->bf16 [n][k];
// [3072,11264) mask int32 -> per-wave lane-mask words (int4 + 4 ballots).
// (Round-7 lesson: mask blocks overlap x/W blocks here; moving them into
// qkv made a serial tail -> reverted.)
// ---------------------------------------------------------------------------
__global__ __launch_bounds__(256) void prep_kernel(
    const float* __restrict__ x,
    const float* __restrict__ Wq, const float* __restrict__ Wk,
    const float* __restrict__ Wv, const float* __restrict__ Wo,
    const int* __restrict__ mask,
    unsigned short* __restrict__ xb, unsigned short* __restrict__ Wt,
    unsigned long long* __restrict__ packed)
{
    __shared__ float tile[64][65];
    const int bid = blockIdx.x;
    const int t   = threadIdx.x;

    if (bid < 2048) {
        // ---- x -> bf16 ----
        size_t i = ((size_t)bid * 256 + t) * 8;
        float4 a = *(const float4*)(x + i);
        float4 b = *(const float4*)(x + i + 4);
        ushort8 o;
        o[0] = f2bf(a.x); o[1] = f2bf(a.y); o[2] = f2bf(a.z); o[3] = f2bf(a.w);
        o[4] = f2bf(b.x); o[5] = f2bf(b.y); o[6] = f2bf(b.z); o[7] = f2bf(b.w);
        *(ushort8*)(xb + i) = o;
    } else if (bid < 3072) {
        // ---- W [k][n] -> Wt [z][n][k] bf16, 64x64 tiles ----
        const int idx = bid - 2048;
        const int n0 = (idx & 15) * 64;
        const int k0 = ((idx >> 4) & 15) * 64;
        const int z  = idx >> 8;
        const float* W = (z == 0) ? Wq : (z == 1) ? Wk : (z == 2) ? Wv : Wo;
        unsigned short* outp = Wt + (size_t)z * Kdim * Ddim;
#pragma unroll
        for (int i = 0; i < 4; ++i) {
            int flat = i * 256 + t;
            int r = flat >> 4;
            int c = (flat & 15) * 4;
            float4 v = *(const float4*)(W + (size_t)(k0 + r) * Ddim + n0 + c);
            tile[r][c] = v.x; tile[r][c+1] = v.y; tile[r][c+2] = v.z; tile[r][c+3] = v.w;
        }
        __syncthreads();
#pragma unroll
        for (int i = 0; i < 16; ++i) {
            int flat = i * 256 + t;
            int n = flat >> 6;
            int k = flat & 63;
            outp[(size_t)(n0 + n) * Kdim + k0 + k] = f2bf(tile[k][n]);
        }
    } else {
        // ---- mask pack: wave group gid=(b,qg,kb); lane (l15,quad) reads int4,
        //      4 ballots give words [gid*4 + r],
        //      bit(lane) = mask[b][qg*16+l15][kb*16+quad*4+r] ----
        const int lane = t & 63;
        const int l15  = lane & 15;
        const int quad = lane >> 4;
        const unsigned int gid = (bid - 3072) * 4 + (t >> 6);
        const int b  = gid >> 14;
        const int qg = (gid >> 7) & 127;
        const int kb = gid & 127;
        int4 mv = *(const int4*)(mask + ((size_t)(b * Sdim) + qg * 16 + l15) * Sdim + kb * 16 + quad * 4);
        unsigned long long w0 = __ballot(mv.x != 0);
        unsigned long long w1 = __ballot(mv.y != 0);
        unsigned long long w2 = __ballot(mv.z != 0);
        unsigned long long w3 = __ballot(mv.w != 0);
        if (lane == 0) {
            unsigned long long* dst = packed + (size_t)gid * 4;
            dst[0] = w0; dst[1] = w1; dst[2] = w2; dst[3] = w3;
        }
    }
}

// ---------------------------------------------------------------------------
// bf16 MFMA GEMM K-loop (m97 structure), 128 x BN tile, BK=64.
// MFMA_NORM: C (lane=n-col, regs=m-rows).  MFMA_SWAP: C^T (lane=m, regs=n).
// ---------------------------------------------------------------------------
#define MFMA_NORM(MT, NT) acc[MT][NT] = __builtin_amdgcn_mfma_f32_16x16x32_bf16(af[MT], bfr[NT], acc[MT][NT], 0, 0, 0)
#define MFMA_SWAP(MT, NT) acc[MT][NT] = __builtin_amdgcn_mfma_f32_16x16x32_bf16(bfr[NT], af[MT], acc[MT][NT], 0, 0, 0)

#define GEMM_KLOOP(APTR, WPTR, NT_TILES, MFMA_STMT)                              \
    for (int kt = 0; kt < 16; ++kt) {                                            \
        const int k0 = kt * 64;                                                  \
        __syncthreads();                                                         \
        _Pragma("unroll")                                                        \
        for (int i = 0; i < 4; ++i) {                                            \
            int flat = i * 256 + t;                                              \
            int row  = flat >> 3;                                                \
            int cg   = (flat & 7) ^ (row & 7);                                   \
            async_ld16(APTR + (size_t)(m0 + row) * Kdim + k0 + cg * 8,           \
                       As + flat * 8);                                           \
        }                                                                        \
        _Pragma("unroll")                                                        \
        for (int i = 0; i < NT_TILES; ++i) {                                     \
            int flat = i * 256 + t;                                              \
            int row  = flat >> 3;                                                \
            int cg   = (flat & 7) ^ (row & 7);                                   \
            async_ld16(WPTR + (size_t)row * Kdim + k0 + cg * 8,                  \
                       Bs + flat * 8);                                           \
        }                                                                        \
        __syncthreads();                                                         \
        _Pragma("unroll")                                                        \
        for (int ks = 0; ks < 2; ++ks) {                                         \
            short8 af[4], bfr[NT_TILES];                                         \
            _Pragma("unroll")                                                    \
            for (int mt = 0; mt < 4; ++mt) {                                     \
                int row = wm * 64 + mt * 16 + l15;                               \
                int ch  = (ks * 4 + quad) ^ (row & 7);                           \
                af[mt] = *(const short8*)(As + row * 64 + ch * 8);               \
            }                                                                    \
            _Pragma("unroll")                                                    \
            for (int nt = 0; nt < NT_TILES; ++nt) {                              \
                int row = wn * (NT_TILES * 16) + nt * 16 + l15;                  \
                int ch  = (ks * 4 + quad) ^ (row & 7);                           \
                bfr[nt] = *(const short8*)(Bs + row * 64 + ch * 8);              \
            }                                                                    \
            _Pragma("unroll")                                                    \
            for (int mt = 0; mt < 4; ++mt)                                       \
                _Pragma("unroll")                                                \
                for (int nt = 0; nt < NT_TILES; ++nt)                            \
                    MFMA_STMT(mt, nt);                                           \
        }                                                                        \
    }

// ---------------------------------------------------------------------------
// Fused QKV projection: grid (24, 32) = 768 blocks. __launch_bounds__(256,4):
// cap 128 VGPR -> 4 blocks/CU (m97-ref compiles at 164 VGPR = 2 blocks/CU;
// barrier-drain stalls need co-resident blocks to hide). XCD-chunked swizzle.
// ---------------------------------------------------------------------------
__global__ __launch_bounds__(256, 4) void qkv_mfma_kernel(
    const unsigned short* __restrict__ A, const unsigned short* __restrict__ Wt,
    const float* __restrict__ bq, const float* __restrict__ bk, const float* __restrict__ bv,
    unsigned short* __restrict__ qo, unsigned short* __restrict__ ko, _Float16* __restrict__ vto)
{
    __shared__ __align__(16) unsigned short As[128 * 64];
    __shared__ __align__(16) unsigned short Bs[128 * 64];
    // XCD swizzle (dispatch round-robins linear bid % 8): lin -> (bx,by)
    const int lin = blockIdx.y * 24 + blockIdx.x;
    const int xcd = lin & 7;
    const int idx = lin >> 3;                 // 0..95
    const int bx  = (xcd & 1) * 12 + idx % 12;
    const int by  = (xcd >> 1) * 8 + idx / 12;
    const int n0   = bx * 128;
    const int m0   = by * 128;
    const int wsel = n0 >> 10;
    const int c0   = n0 & 1023;
    const unsigned short* Wp = Wt + (size_t)wsel * Kdim * Ddim + (size_t)c0 * Kdim;

    const int t    = threadIdx.x;
    const int lane = t & 63;
    const int w    = t >> 6;
    const int quad = lane >> 4;
    const int l15  = lane & 15;
    const int wm   = w & 1;
    const int wn   = w >> 1;
    floatx4 acc[4][4];
#pragma unroll
    for (int mt = 0; mt < 4; ++mt)
#pragma unroll
        for (int nt = 0; nt < 4; ++nt) acc[mt][nt] = (floatx4){0.f, 0.f, 0.f, 0.f};

    if (wsel < 2) {
        GEMM_KLOOP(A, Wp, 4, MFMA_SWAP)
        const float* bias = wsel ? bk : bq;
        unsigned short* outp = wsel ? ko : qo;
        const float qsc = wsel ? 1.0f : 0.18033688011112042f;  // q: 0.125*log2(e)
#pragma unroll
        for (int mt = 0; mt < 4; ++mt) {
            int m    = m0 + wm * 64 + mt * 16 + l15;  // s-row
            int bidx = m >> 11;
            int s    = m & 2047;
#pragma unroll
            for (int nt = 0; nt < 4; ++nt) {
                int c = c0 + wn * 64 + nt * 16 + quad * 4;  // 4 contiguous cols
                float4 bb = *(const float4*)(bias + c);
                int h  = c >> 6;
                int hd = c & 63;
                ushort4v o;
                o[0] = f2bf((acc[mt][nt][0] + bb.x) * qsc);
                o[1] = f2bf((acc[mt][nt][1] + bb.y) * qsc);
                o[2] = f2bf((acc[mt][nt][2] + bb.z) * qsc);
                o[3] = f2bf((acc[mt][nt][3] + bb.w) * qsc);
                *(ushort4v*)(outp + ((size_t)(bidx * Hnum + h) * Sdim + s) * HDdim + hd) = o;
            }
        }
    } else {
        GEMM_KLOOP(A, Wp, 4, MFMA_NORM)
#pragma unroll
        for (int nt = 0; nt < 4; ++nt) {
            int c = c0 + wn * 64 + nt * 16 + l15;
            float bb = bv[c];
            int h  = c >> 6;
            int hd = c & 63;
#pragma unroll
            for (int mt = 0; mt < 4; ++mt) {
                int m    = m0 + wm * 64 + mt * 16 + quad * 4;  // 4 contiguous s
                int bidx = m >> 11;
                int s    = m & 2047;
                half4 o;
#pragma unroll
                for (int r = 0; r < 4; ++r) o[r] = (_Float16)(acc[mt][nt][r] + bb);
                *(half4*)(vto + ((size_t)(bidx * Hnum + h) * HDdim + hd) * Sdim + s) = o;
            }
        }
    }
}

// ---------------------------------------------------------------------------
// Output projection (operand-swapped), 128x64 tiles: grid (16, 32) = 512
// blocks. __launch_bounds__(256,4) -> 4 blocks/CU (needs ~95 VGPR, safe).
// XCD swizzle: each XCD owns 4 consecutive y x all x.
// ---------------------------------------------------------------------------
__global__ __launch_bounds__(256, 4) void out_mfma_kernel(
    const unsigned short* __restrict__ A, const unsigned short* __restrict__ Wt,
    const float* __restrict__ bias, float* __restrict__ out)
{
    __shared__ __align__(16) unsigned short As[128 * 64];
    __shared__ __align__(16) unsigned short Bs[64 * 64];
    const int lin = blockIdx.y * 16 + blockIdx.x;
    const int xcd = lin & 7;
    const int idx = lin >> 3;                 // 0..63
    const int bx  = idx & 15;
    const int by  = xcd * 4 + (idx >> 4);
    const int n0 = bx * 64;
    const int m0 = by * 128;
    const unsigned short* Wp = Wt + (size_t)3 * Kdim * Ddim + (size_t)n0 * Kdim;

    const int t    = threadIdx.x;
    const int lane = t & 63;
    const int w    = t >> 6;
    const int quad = lane >> 4;
    const int l15  = lane & 15;
    const int wm   = w & 1;
    const int wn   = w >> 1;
    floatx4 acc[4][2];
#pragma unroll
    for (int mt = 0; mt < 4; ++mt)
#pragma unroll
        for (int nt = 0; nt < 2; ++nt) acc[mt][nt] = (floatx4){0.f, 0.f, 0.f, 0.f};

    GEMM_KLOOP(A, Wp, 2, MFMA_SWAP)

#pragma unroll
    for (int mt = 0; mt < 4; ++mt) {
        int m = m0 + wm * 64 + mt * 16 + l15;  // s-row
#pragma unroll
        for (int nt = 0; nt < 2; ++nt) {
            int c = n0 + wn * 32 + nt * 16 + quad * 4;
            float4 bb = *(const float4*)(bias + c);
            float4 o = make_float4(acc[mt][nt][0] + bb.x, acc[mt][nt][1] + bb.y,
                                   acc[mt][nt][2] + bb.z, acc[mt][nt][3] + bb.w);
            *(float4*)(out + (size_t)m * Ddim + c) = o;
        }
    }
}

// ---------------------------------------------------------------------------
// MFMA flash attention v9 (unchanged, best measured 75.9us): v6b 2x2 wave
// decomposition + T5 s_setprio around QK/PV MFMA clusters. Wave (wq,wk) owns
// 32 q-rows x 32 keys; grid 1024 (4 blocks/CU). Same-bh blocks 32 apart ==
// same XCD under round-robin: KV L2-clustered.
// ---------------------------------------------------------------------------
__global__ __launch_bounds__(256, 4) void attn_mfma_kernel(
    const unsigned short* __restrict__ q, const unsigned short* __restrict__ k,
    const _Float16* __restrict__ vt, const unsigned long long* __restrict__ pmask,
    unsigned short* __restrict__ ctx)
{
    __shared__ __align__(16) unsigned short Ks[2][64 * 64];  // [key][hd], swizzled
    __shared__ __align__(16) _Float16       Vs[2][64 * 64];  // [hd][key], swizzled

    const int t    = threadIdx.x;
    const int w    = t >> 6;
    const int lane = t & 63;
    const int quad = lane >> 4;
    const int l15  = lane & 15;
    const int bid  = blockIdx.x;
    const int bh   = bid & 31;
    const int qseg = bid >> 5;          // 0..31
    const int b    = bh >> 4;
    const int h    = bh & 15;
    const int wq   = w & 1;             // q-half of the block's 64 rows
    const int wk   = w >> 1;            // key-half of each 64-key tile
    const int qrow0 = qseg * 64 + wq * 32;   // 32 q-rows per wave (g=0,1)

    const unsigned short* qp = q  + (size_t)bh * Sdim * HDdim;
    const unsigned short* kp = k  + (size_t)bh * Sdim * HDdim;
    const _Float16*       vp = vt + (size_t)bh * HDdim * Sdim;

    // wave-uniform mask base (scalar loads feed v_cndmask's "s" operand)
    const int qg0 = __builtin_amdgcn_readfirstlane(qrow0 >> 4);
    const int wku = __builtin_amdgcn_readfirstlane(wk);
    const unsigned long long* __restrict__ pm =
        pmask + ((size_t)(b * 128 + qg0) * 128) * 4 + wku * 8;

    short8 qf[2][2];
#pragma unroll
    for (int g = 0; g < 2; ++g)
#pragma unroll
        for (int ks = 0; ks < 2; ++ks)
            qf[g][ks] = *(const short8*)(qp + (size_t)(qrow0 + g * 16 + l15) * HDdim + ks * 32 + quad * 8);

    floatx4 acc[2][4];
    floatx4 accl[2];
#pragma unroll
    for (int g = 0; g < 2; ++g) {
        accl[g] = (floatx4){0.f, 0.f, 0.f, 0.f};
#pragma unroll
        for (int hs = 0; hs < 4; ++hs) acc[g][hs] = (floatx4){0.f, 0.f, 0.f, 0.f};
    }
    const half4 ones = {(_Float16)1.f, (_Float16)1.f, (_Float16)1.f, (_Float16)1.f};

    // stage key-tile into buf: 256 threads x (2 K + 2 V) DMA insts.
    auto stage = [&](int buf, int key0) {
#pragma unroll
        for (int i = 0; i < 2; ++i) {
            int flat = i * 256 + t;
            int row  = flat >> 3;
            int cg   = (flat & 7) ^ (row & 7);
            async_ld16(kp + (size_t)(key0 + row) * HDdim + cg * 8, &Ks[buf][flat * 8]);
        }
#pragma unroll
        for (int i = 0; i < 2; ++i) {
            int flat = i * 256 + t;
            int row  = flat >> 3;
            int cg   = (flat & 7) ^ (row & 7);
            async_ld16((const unsigned short*)(vp + (size_t)row * Sdim + key0 + cg * 8),
                       (unsigned short*)&Vs[buf][flat * 8]);
        }
    };

    stage(0, 0);

#pragma unroll 2
    for (int kt = 0; kt < 32; ++kt) {
        const int cur = kt & 1;
        __syncthreads();
        if (kt < 31) stage(cur ^ 1, (kt + 1) * 64);

        // wave's key-half of K: rows [wk*32, wk*32+32)
        short8 kf[2][2];
#pragma unroll
        for (int ks = 0; ks < 2; ++ks)
#pragma unroll
            for (int sub = 0; sub < 2; ++sub) {
                int row = wk * 32 + sub * 16 + l15;
                int ch  = (ks * 4 + quad) ^ (row & 7);
                kf[ks][sub] = *(const short8*)&Ks[cur][row * 64 + ch * 8];
            }
        // wave's key-half of V: key cols [wk*32, wk*32+32)
        half4 vf[4][2];
#pragma unroll
        for (int hs = 0; hs < 4; ++hs)
#pragma unroll
            for (int c = 0; c < 2; ++c) {
                int row = hs * 16 + l15;
                int cc  = (wk * 2 + c) * 2 + (quad >> 1);
                int ch  = cc ^ (row & 7);
                vf[hs][c] = *(const half4*)&Vs[cur][row * 64 + ch * 8 + (quad & 1) * 4];
            }

        floatx4 sc[2][2];
#pragma unroll
        for (int g = 0; g < 2; ++g)
#pragma unroll
            for (int sub = 0; sub < 2; ++sub) sc[g][sub] = (floatx4){0.f, 0.f, 0.f, 0.f};
        __builtin_amdgcn_s_setprio(1);
#pragma unroll
        for (int ks = 0; ks < 2; ++ks)
#pragma unroll
            for (int sub = 0; sub < 2; ++sub)
#pragma unroll
                for (int g = 0; g < 2; ++g)
                    sc[g][sub] = __builtin_amdgcn_mfma_f32_16x16x32_bf16(
                        kf[ks][sub], qf[g][ks], sc[g][sub], 0, 0, 0);
        __builtin_amdgcn_s_setprio(0);

        // sc[g][sub][r] = score[q=qrow0+g*16+l15][key = kt*64 + wk*32 + sub*16 + quad*4 + r]
        half4 pf[2][2];
#pragma unroll
        for (int g = 0; g < 2; ++g) {
            const unsigned long long* __restrict__ pg = pm + g * 512 + kt * 16;
#pragma unroll
            for (int c = 0; c < 2; ++c) {
                float pv[4];
#pragma unroll
                for (int r = 0; r < 4; ++r) {
                    float p = exp2f(sc[g][c][r]);
                    unsigned long long wmask = pg[c * 4 + r];
                    asm("v_cndmask_b32 %0, 0, %1, %2" : "=v"(pv[r]) : "v"(p), "s"(wmask));
                }
                half2v lo = __builtin_bit_cast(half2v, __builtin_amdgcn_cvt_pkrtz(pv[0], pv[1]));
                half2v hi = __builtin_bit_cast(half2v, __builtin_amdgcn_cvt_pkrtz(pv[2], pv[3]));
                pf[g][c][0] = lo[0]; pf[g][c][1] = lo[1];
                pf[g][c][2] = hi[0]; pf[g][c][3] = hi[1];
            }
        }

        __builtin_amdgcn_s_setprio(1);
#pragma unroll
        for (int c = 0; c < 2; ++c) {
#pragma unroll
            for (int hs = 0; hs < 4; ++hs)
#pragma unroll
                for (int g = 0; g < 2; ++g)
                    acc[g][hs] = __builtin_amdgcn_mfma_f32_16x16x16f16(
                        vf[hs][c], pf[g][c], acc[g][hs], 0, 0, 0);
#pragma unroll
            for (int g = 0; g < 2; ++g)
                accl[g] = __builtin_amdgcn_mfma_f32_16x16x16f16(
                    ones, pf[g][c], accl[g], 0, 0, 0);
        }
        __builtin_amdgcn_s_setprio(0);
    }

    // ---- cross-wave (wk) reduction of partial ctx / l through dead LDS ----
    __syncthreads();
    float* red  = (float*)&Ks[0][0];   // 16 slots x 64 lanes x floatx4 = 16KB
    float* redl = (float*)&Vs[0][0];   // 4 slots x 64 lanes x f32 = 1KB
    if (wk == 1) {
#pragma unroll
        for (int g = 0; g < 2; ++g) {
#pragma unroll
            for (int hs = 0; hs < 4; ++hs)
                *(floatx4*)&red[((((wq * 2) + g) * 4 + hs) * 64 + lane) * 4] = acc[g][hs];
            redl[(wq * 2 + g) * 64 + lane] = accl[g][0];
        }
    }
    __syncthreads();
    if (wk == 0) {
#pragma unroll
        for (int g = 0; g < 2; ++g) {
            float lsum = accl[g][0] + redl[(wq * 2 + g) * 64 + lane];
            float inv  = 1.0f / fmaxf(lsum, 1e-30f);
            int row = qrow0 + g * 16 + l15;
#pragma unroll
            for (int hs = 0; hs < 4; ++hs) {
                floatx4 o4 = acc[g][hs] + *(const floatx4*)&red[((((wq * 2) + g) * 4 + hs) * 64 + lane) * 4];
                ushort4v o;
#pragma unroll
                for (int r = 0; r < 4; ++r) o[r] = f2bf(o4[r] * inv);
                *(ushort4v*)(ctx + (size_t)(b * Sdim + row) * Ddim + h * 64 + hs * 16 + quad * 4) = o;
            }
        }
    }
}

// ---------------------------------------------------------------------------
extern "C" void kernel_launch(void* const* d_in, const int* in_sizes, int n_in,
                              void* d_out, int out_size, void* d_ws, size_t ws_size,
                              hipStream_t stream) {
    const float* x   = (const float*)d_in[0];
    const float* Wq  = (const float*)d_in[1];
    const float* bq  = (const float*)d_in[2];
    const float* Wk  = (const float*)d_in[3];
    const float* bk  = (const float*)d_in[4];
    const float* Wv  = (const float*)d_in[5];
    const float* bv  = (const float*)d_in[6];
    const float* Wo  = (const float*)d_in[7];
    const float* bo  = (const float*)d_in[8];
    // d_in[9] cross_modal_weights: softmax-shift-invariant -> unused
    const int*  mask = (const int*)d_in[10];
    // d_in[11] modality_info: unused by the reference
    float* out = (float*)d_out;

    char* ws = (char*)d_ws;
    unsigned short* xb  = (unsigned short*)(ws);                         // 8 MB
    unsigned short* Wt  = (unsigned short*)(ws + (size_t)8  * 1048576);  // 8 MB
    unsigned short* qb  = (unsigned short*)(ws + (size_t)16 * 1048576);  // 8 MB
    unsigned short* kb  = (unsigned short*)(ws + (size_t)24 * 1048576);  // 8 MB
    _Float16*       vtb = (_Float16*)     (ws + (size_t)32 * 1048576);   // 8 MB f16 [bh][hd][s]
    unsigned long long* pmk = (unsigned long long*)(ws + (size_t)40 * 1048576); // 1 MB
    unsigned short* ctxb = xb;  // alias: xb consumed before attn writes ctx

    prep_kernel<<<dim3(11264), 256, 0, stream>>>(x, Wq, Wk, Wv, Wo, mask, xb, Wt, pmk);
    qkv_mfma_kernel<<<dim3(24, 32), 256, 0, stream>>>(xb, Wt, bq, bk, bv, qb, kb, vtb);
    attn_mfma_kernel<<<dim3(1024), 256, 0, stream>>>(qb, kb, vtb, pmk, ctxb);
    out_mfma_kernel<<<dim3(16, 32), 256, 0, stream>>>(ctxb, Wt, bo, out);
}

// Round 10
// 228.196 us; speedup vs baseline: 1.0527x; 1.0171x over previous
//
#include <hip/hip_runtime.h>
#include <math.h>

#define Bdim 2
#define Sdim 2048
#define Ddim 1024
#define Hnum 16
#define HDdim 64
#define Kdim 1024

using short8   = __attribute__((ext_vector_type(8))) short;
using ushort8  = __attribute__((ext_vector_type(8))) unsigned short;
using ushort4v = __attribute__((ext_vector_type(4))) unsigned short;
using floatx4  = __attribute__((ext_vector_type(4))) float;
using half4    = __attribute__((ext_vector_type(4))) _Float16;
using half2v   = __attribute__((ext_vector_type(2))) _Float16;

__device__ __forceinline__ unsigned short f2bf(float f) {
    __bf16 b = (__bf16)f;
    return __builtin_bit_cast(unsigned short, b);
}

// async global->LDS, 16B per lane. LDS dest is wave-uniform base + lane*16.
__device__ __forceinline__ void async_ld16(const unsigned short* g, unsigned short* l) {
    __builtin_amdgcn_global_load_lds(
        (const __attribute__((address_space(1))) unsigned int*)(g),
        (__attribute__((address_space(3))) unsigned int*)(l), 16, 0, 0);
}

// ---------------------------------------------------------------------------
// Fused prep: [0,2048) x fp32->bf16; [2048,3072) W transpose->bf16 [n][k];
// [3072,11264) mask int32 -> per-wave lane-mask words (int4 + 4 ballots).
// ---------------------------------------------------------------------------
__global__ __launch_bounds__(256) void prep_kernel(
    const float* __restrict__ x,
    const float* __restrict__ Wq, const float* __restrict__ Wk,
    const float* __restrict__ Wv, const float* __restrict__ Wo,
    const int* __restrict__ mask,
    unsigned short* __restrict__ xb, unsigned short* __restrict__ Wt,
    unsigned long long* __restrict__ packed)
{
    __shared__ float tile[64][65];
    const int bid = blockIdx.x;
    const int t   = threadIdx.x;

    if (bid < 2048) {
        // ---- x -> bf16 ----
        size_t i = ((size_t)bid * 256 + t) * 8;
        float4 a = *(const float4*)(x + i);
        float4 b = *(const float4*)(x + i + 4);
        ushort8 o;
        o[0] = f2bf(a.x); o[1] = f2bf(a.y); o[2] = f2bf(a.z); o[3] = f2bf(a.w);
        o[4] = f2bf(b.x); o[5] = f2bf(b.y); o[6] = f2bf(b.z); o[7] = f2bf(b.w);
        *(ushort8*)(xb + i) = o;
    } else if (bid < 3072) {
        // ---- W [k][n] -> Wt [z][n][k] bf16, 64x64 tiles ----
        const int idx = bid - 2048;
        const int n0 = (idx & 15) * 64;
        const int k0 = ((idx >> 4) & 15) * 64;
        const int z  = idx >> 8;
        const float* W = (z == 0) ? Wq : (z == 1) ? Wk : (z == 2) ? Wv : Wo;
        unsigned short* outp = Wt + (size_t)z * Kdim * Ddim;
#pragma unroll
        for (int i = 0; i < 4; ++i) {
            int flat = i * 256 + t;
            int r = flat >> 4;
            int c = (flat & 15) * 4;
            float4 v = *(const float4*)(W + (size_t)(k0 + r) * Ddim + n0 + c);
            tile[r][c] = v.x; tile[r][c+1] = v.y; tile[r][c+2] = v.z; tile[r][c+3] = v.w;
        }
        __syncthreads();
#pragma unroll
        for (int i = 0; i < 16; ++i) {
            int flat = i * 256 + t;
            int n = flat >> 6;
            int k = flat & 63;
            outp[(size_t)(n0 + n) * Kdim + k0 + k] = f2bf(tile[k][n]);
        }
    } else {
        // ---- mask pack: wave group gid=(b,qg,kb); lane (l15,quad) reads int4,
        //      4 ballots give words [gid*4 + r],
        //      bit(lane) = mask[b][qg*16+l15][kb*16+quad*4+r] ----
        const int lane = t & 63;
        const int l15  = lane & 15;
        const int quad = lane >> 4;
        const unsigned int gid = (bid - 3072) * 4 + (t >> 6);
        const int b  = gid >> 14;
        const int qg = (gid >> 7) & 127;
        const int kb = gid & 127;
        int4 mv = *(const int4*)(mask + ((size_t)(b * Sdim) + qg * 16 + l15) * Sdim + kb * 16 + quad * 4);
        unsigned long long w0 = __ballot(mv.x != 0);
        unsigned long long w1 = __ballot(mv.y != 0);
        unsigned long long w2 = __ballot(mv.z != 0);
        unsigned long long w3 = __ballot(mv.w != 0);
        if (lane == 0) {
            unsigned long long* dst = packed + (size_t)gid * 4;
            dst[0] = w0; dst[1] = w1; dst[2] = w2; dst[3] = w3;
        }
    }
}

// ---------------------------------------------------------------------------
// bf16 MFMA GEMM K-loop (m97 structure), 128 x BN tile, BK=64.
// MFMA_NORM: C (lane=n-col, regs=m-rows).  MFMA_SWAP: C^T (lane=m, regs=n).
// ---------------------------------------------------------------------------
#define MFMA_NORM(MT, NT) acc[MT][NT] = __builtin_amdgcn_mfma_f32_16x16x32_bf16(af[MT], bfr[NT], acc[MT][NT], 0, 0, 0)
#define MFMA_SWAP(MT, NT) acc[MT][NT] = __builtin_amdgcn_mfma_f32_16x16x32_bf16(bfr[NT], af[MT], acc[MT][NT], 0, 0, 0)

#define GEMM_KLOOP(APTR, WPTR, NT_TILES, MFMA_STMT)                              \
    for (int kt = 0; kt < 16; ++kt) {                                            \
        const int k0 = kt * 64;                                                  \
        __syncthreads();                                                         \
        _Pragma("unroll")                                                        \
        for (int i = 0; i < 4; ++i) {                                            \
            int flat = i * 256 + t;                                              \
            int row  = flat >> 3;                                                \
            int cg   = (flat & 7) ^ (row & 7);                                   \
            async_ld16(APTR + (size_t)(m0 + row) * Kdim + k0 + cg * 8,           \
                       As + flat * 8);                                           \
        }                                                                        \
        _Pragma("unroll")                                                        \
        for (int i = 0; i < NT_TILES; ++i) {                                     \
            int flat = i * 256 + t;                                              \
            int row  = flat >> 3;                                                \
            int cg   = (flat & 7) ^ (row & 7);                                   \
            async_ld16(WPTR + (size_t)row * Kdim + k0 + cg * 8,                  \
                       Bs + flat * 8);                                           \
        }                                                                        \
        __syncthreads();                                                         \
        _Pragma("unroll")                                                        \
        for (int ks = 0; ks < 2; ++ks) {                                         \
            short8 af[4], bfr[NT_TILES];                                         \
            _Pragma("unroll")                                                    \
            for (int mt = 0; mt < 4; ++mt) {                                     \
                int row = wm * 64 + mt * 16 + l15;                               \
                int ch  = (ks * 4 + quad) ^ (row & 7);                           \
                af[mt] = *(const short8*)(As + row * 64 + ch * 8);               \
            }                                                                    \
            _Pragma("unroll")                                                    \
            for (int nt = 0; nt < NT_TILES; ++nt) {                              \
                int row = wn * (NT_TILES * 16) + nt * 16 + l15;                  \
                int ch  = (ks * 4 + quad) ^ (row & 7);                           \
                bfr[nt] = *(const short8*)(Bs + row * 64 + ch * 8);              \
            }                                                                    \
            _Pragma("unroll")                                                    \
            for (int mt = 0; mt < 4; ++mt)                                       \
                _Pragma("unroll")                                                \
                for (int nt = 0; nt < NT_TILES; ++nt)                            \
                    MFMA_STMT(mt, nt);                                           \
        }                                                                        \
    }

// ---------------------------------------------------------------------------
// Fused QKV projection: grid (24, 32) = 768 blocks, launch_bounds(256,4)
// (128-VGPR cap -> 4 blocks/CU). XCD-chunked swizzle (12x8 rectangles).
// ---------------------------------------------------------------------------
__global__ __launch_bounds__(256, 4) void qkv_mfma_kernel(
    const unsigned short* __restrict__ A, const unsigned short* __restrict__ Wt,
    const float* __restrict__ bq, const float* __restrict__ bk, const float* __restrict__ bv,
    unsigned short* __restrict__ qo, unsigned short* __restrict__ ko, _Float16* __restrict__ vto)
{
    __shared__ __align__(16) unsigned short As[128 * 64];
    __shared__ __align__(16) unsigned short Bs[128 * 64];
    // XCD swizzle (dispatch round-robins linear bid % 8): lin -> (bx,by)
    const int lin = blockIdx.y * 24 + blockIdx.x;
    const int xcd = lin & 7;
    const int idx = lin >> 3;                 // 0..95
    const int bx  = (xcd & 1) * 12 + idx % 12;
    const int by  = (xcd >> 1) * 8 + idx / 12;
    const int n0   = bx * 128;
    const int m0   = by * 128;
    const int wsel = n0 >> 10;
    const int c0   = n0 & 1023;
    const unsigned short* Wp = Wt + (size_t)wsel * Kdim * Ddim + (size_t)c0 * Kdim;

    const int t    = threadIdx.x;
    const int lane = t & 63;
    const int w    = t >> 6;
    const int quad = lane >> 4;
    const int l15  = lane & 15;
    const int wm   = w & 1;
    const int wn   = w >> 1;
    floatx4 acc[4][4];
#pragma unroll
    for (int mt = 0; mt < 4; ++mt)
#pragma unroll
        for (int nt = 0; nt < 4; ++nt) acc[mt][nt] = (floatx4){0.f, 0.f, 0.f, 0.f};

    if (wsel < 2) {
        GEMM_KLOOP(A, Wp, 4, MFMA_SWAP)
        const float* bias = wsel ? bk : bq;
        unsigned short* outp = wsel ? ko : qo;
        const float qsc = wsel ? 1.0f : 0.18033688011112042f;  // q: 0.125*log2(e)
#pragma unroll
        for (int mt = 0; mt < 4; ++mt) {
            int m    = m0 + wm * 64 + mt * 16 + l15;  // s-row
            int bidx = m >> 11;
            int s    = m & 2047;
#pragma unroll
            for (int nt = 0; nt < 4; ++nt) {
                int c = c0 + wn * 64 + nt * 16 + quad * 4;  // 4 contiguous cols
                float4 bb = *(const float4*)(bias + c);
                int h  = c >> 6;
                int hd = c & 63;
                ushort4v o;
                o[0] = f2bf((acc[mt][nt][0] + bb.x) * qsc);
                o[1] = f2bf((acc[mt][nt][1] + bb.y) * qsc);
                o[2] = f2bf((acc[mt][nt][2] + bb.z) * qsc);
                o[3] = f2bf((acc[mt][nt][3] + bb.w) * qsc);
                *(ushort4v*)(outp + ((size_t)(bidx * Hnum + h) * Sdim + s) * HDdim + hd) = o;
            }
        }
    } else {
        GEMM_KLOOP(A, Wp, 4, MFMA_NORM)
#pragma unroll
        for (int nt = 0; nt < 4; ++nt) {
            int c = c0 + wn * 64 + nt * 16 + l15;
            float bb = bv[c];
            int h  = c >> 6;
            int hd = c & 63;
#pragma unroll
            for (int mt = 0; mt < 4; ++mt) {
                int m    = m0 + wm * 64 + mt * 16 + quad * 4;  // 4 contiguous s
                int bidx = m >> 11;
                int s    = m & 2047;
                half4 o;
#pragma unroll
                for (int r = 0; r < 4; ++r) o[r] = (_Float16)(acc[mt][nt][r] + bb);
                *(half4*)(vto + ((size_t)(bidx * Hnum + h) * HDdim + hd) * Sdim + s) = o;
            }
        }
    }
}

// ---------------------------------------------------------------------------
// Output projection (operand-swapped), 128x64 tiles: grid (16, 32) = 512
// blocks, launch_bounds(256,4). XCD swizzle: each XCD owns 4 consecutive y.
// ---------------------------------------------------------------------------
__global__ __launch_bounds__(256, 4) void out_mfma_kernel(
    const unsigned short* __restrict__ A, const unsigned short* __restrict__ Wt,
    const float* __restrict__ bias, float* __restrict__ out)
{
    __shared__ __align__(16) unsigned short As[128 * 64];
    __shared__ __align__(16) unsigned short Bs[64 * 64];
    const int lin = blockIdx.y * 16 + blockIdx.x;
    const int xcd = lin & 7;
    const int idx = lin >> 3;                 // 0..63
    const int bx  = idx & 15;
    const int by  = xcd * 4 + (idx >> 4);
    const int n0 = bx * 64;
    const int m0 = by * 128;
    const unsigned short* Wp = Wt + (size_t)3 * Kdim * Ddim + (size_t)n0 * Kdim;

    const int t    = threadIdx.x;
    const int lane = t & 63;
    const int w    = t >> 6;
    const int quad = lane >> 4;
    const int l15  = lane & 15;
    const int wm   = w & 1;
    const int wn   = w >> 1;
    floatx4 acc[4][2];
#pragma unroll
    for (int mt = 0; mt < 4; ++mt)
#pragma unroll
        for (int nt = 0; nt < 2; ++nt) acc[mt][nt] = (floatx4){0.f, 0.f, 0.f, 0.f};

    GEMM_KLOOP(A, Wp, 2, MFMA_SWAP)

#pragma unroll
    for (int mt = 0; mt < 4; ++mt) {
        int m = m0 + wm * 64 + mt * 16 + l15;  // s-row
#pragma unroll
        for (int nt = 0; nt < 2; ++nt) {
            int c = n0 + wn * 32 + nt * 16 + quad * 4;
            float4 bb = *(const float4*)(bias + c);
            float4 o = make_float4(acc[mt][nt][0] + bb.x, acc[mt][nt][1] + bb.y,
                                   acc[mt][nt][2] + bb.z, acc[mt][nt][3] + bb.w);
            *(float4*)(out + (size_t)m * Ddim + c) = o;
        }
    }
}

// ---------------------------------------------------------------------------
// MFMA flash attention v12: v9 per-wave structure, 512-thread blocks.
// 8 waves (wq 0..3, wk 0..1) cover 128 q-rows; grid 512 (2 blocks/CU,
// 16 waves/CU -- occupancy unchanged vs v9) but K/V staging per CU per kt
// halves (32KB vs 64KB): aggregate staged L2 traffic 512MB -> 256MB.
// Rationale: staged DMA (~26 GB/s/CU sustained, ~half per-CU L2 BW) is
// ~40% of the per-kt critical path; 32 blocks/bh staged identical K/V.
// Per-wave work/registers identical to v9 (~64 VGPR; launch_bounds(512,4)
// = 128-VGPR cap, no spill risk). Epilogue reduction over wk through dead
// Ks (hs 0,1) + Vs (hs 2,3) + 2KB redl.
// ---------------------------------------------------------------------------
__global__ __launch_bounds__(512, 4) void attn_mfma_kernel(
    const unsigned short* __restrict__ q, const unsigned short* __restrict__ k,
    const _Float16* __restrict__ vt, const unsigned long long* __restrict__ pmask,
    unsigned short* __restrict__ ctx)
{
    __shared__ __align__(16) unsigned short Ks[2][64 * 64];  // [key][hd], swizzled
    __shared__ __align__(16) _Float16       Vs[2][64 * 64];  // [hd][key], swizzled
    __shared__ float redl[512];

    const int t    = threadIdx.x;
    const int w    = t >> 6;            // 0..7
    const int lane = t & 63;
    const int quad = lane >> 4;
    const int l15  = lane & 15;
    const int bid  = blockIdx.x;
    const int bh   = bid & 31;
    const int qseg = bid >> 5;          // 0..15
    const int b    = bh >> 4;
    const int h    = bh & 15;
    const int wq   = w & 3;             // q-quarter of the block's 128 rows
    const int wk   = w >> 2;            // key-half of each 64-key tile
    const int qrow0 = qseg * 128 + wq * 32;   // 32 q-rows per wave (g=0,1)

    const unsigned short* qp = q  + (size_t)bh * Sdim * HDdim;
    const unsigned short* kp = k  + (size_t)bh * Sdim * HDdim;
    const _Float16*       vp = vt + (size_t)bh * HDdim * Sdim;

    // wave-uniform mask base (scalar loads feed v_cndmask's "s" operand)
    const int qg0 = __builtin_amdgcn_readfirstlane(qrow0 >> 4);
    const int wku = __builtin_amdgcn_readfirstlane(wk);
    const unsigned long long* __restrict__ pm =
        pmask + ((size_t)(b * 128 + qg0) * 128) * 4 + wku * 8;

    short8 qf[2][2];
#pragma unroll
    for (int g = 0; g < 2; ++g)
#pragma unroll
        for (int ks = 0; ks < 2; ++ks)
            qf[g][ks] = *(const short8*)(qp + (size_t)(qrow0 + g * 16 + l15) * HDdim + ks * 32 + quad * 8);

    floatx4 acc[2][4];
    floatx4 accl[2];
#pragma unroll
    for (int g = 0; g < 2; ++g) {
        accl[g] = (floatx4){0.f, 0.f, 0.f, 0.f};
#pragma unroll
        for (int hs = 0; hs < 4; ++hs) acc[g][hs] = (floatx4){0.f, 0.f, 0.f, 0.f};
    }
    const half4 ones = {(_Float16)1.f, (_Float16)1.f, (_Float16)1.f, (_Float16)1.f};

    // stage key-tile into buf: 512 threads x (1 K + 1 V) DMA insts = 16KB.
    auto stage = [&](int buf, int key0) {
        int row = t >> 3;                    // 0..63
        int cg  = (t & 7) ^ (row & 7);
        async_ld16(kp + (size_t)(key0 + row) * HDdim + cg * 8, &Ks[buf][t * 8]);
        async_ld16((const unsigned short*)(vp + (size_t)row * Sdim + key0 + cg * 8),
                   (unsigned short*)&Vs[buf][t * 8]);
    };

    stage(0, 0);

#pragma unroll 2
    for (int kt = 0; kt < 32; ++kt) {
        const int cur = kt & 1;
        __syncthreads();
        if (kt < 31) stage(cur ^ 1, (kt + 1) * 64);

        // wave's key-half of K: rows [wk*32, wk*32+32)
        short8 kf[2][2];
#pragma unroll
        for (int ks = 0; ks < 2; ++ks)
#pragma unroll
            for (int sub = 0; sub < 2; ++sub) {
                int row = wk * 32 + sub * 16 + l15;
                int ch  = (ks * 4 + quad) ^ (row & 7);
                kf[ks][sub] = *(const short8*)&Ks[cur][row * 64 + ch * 8];
            }
        // wave's key-half of V: key cols [wk*32, wk*32+32)
        half4 vf[4][2];
#pragma unroll
        for (int hs = 0; hs < 4; ++hs)
#pragma unroll
            for (int c = 0; c < 2; ++c) {
                int row = hs * 16 + l15;
                int cc  = (wk * 2 + c) * 2 + (quad >> 1);
                int ch  = cc ^ (row & 7);
                vf[hs][c] = *(const half4*)&Vs[cur][row * 64 + ch * 8 + (quad & 1) * 4];
            }

        floatx4 sc[2][2];
#pragma unroll
        for (int g = 0; g < 2; ++g)
#pragma unroll
            for (int sub = 0; sub < 2; ++sub) sc[g][sub] = (floatx4){0.f, 0.f, 0.f, 0.f};
        __builtin_amdgcn_s_setprio(1);
#pragma unroll
        for (int ks = 0; ks < 2; ++ks)
#pragma unroll
            for (int sub = 0; sub < 2; ++sub)
#pragma unroll
                for (int g = 0; g < 2; ++g)
                    sc[g][sub] = __builtin_amdgcn_mfma_f32_16x16x32_bf16(
                        kf[ks][sub], qf[g][ks], sc[g][sub], 0, 0, 0);
        __builtin_amdgcn_s_setprio(0);

        // sc[g][sub][r] = score[q=qrow0+g*16+l15][key = kt*64 + wk*32 + sub*16 + quad*4 + r]
        half4 pf[2][2];
#pragma unroll
        for (int g = 0; g < 2; ++g) {
            const unsigned long long* __restrict__ pg = pm + g * 512 + kt * 16;
#pragma unroll
            for (int c = 0; c < 2; ++c) {
                float pv[4];
#pragma unroll
                for (int r = 0; r < 4; ++r) {
                    float p = exp2f(sc[g][c][r]);
                    unsigned long long wmask = pg[c * 4 + r];
                    asm("v_cndmask_b32 %0, 0, %1, %2" : "=v"(pv[r]) : "v"(p), "s"(wmask));
                }
                half2v lo = __builtin_bit_cast(half2v, __builtin_amdgcn_cvt_pkrtz(pv[0], pv[1]));
                half2v hi = __builtin_bit_cast(half2v, __builtin_amdgcn_cvt_pkrtz(pv[2], pv[3]));
                pf[g][c][0] = lo[0]; pf[g][c][1] = lo[1];
                pf[g][c][2] = hi[0]; pf[g][c][3] = hi[1];
            }
        }

        __builtin_amdgcn_s_setprio(1);
#pragma unroll
        for (int c = 0; c < 2; ++c) {
#pragma unroll
            for (int hs = 0; hs < 4; ++hs)
#pragma unroll
                for (int g = 0; g < 2; ++g)
                    acc[g][hs] = __builtin_amdgcn_mfma_f32_16x16x16f16(
                        vf[hs][c], pf[g][c], acc[g][hs], 0, 0, 0);
#pragma unroll
            for (int g = 0; g < 2; ++g)
                accl[g] = __builtin_amdgcn_mfma_f32_16x16x16f16(
                    ones, pf[g][c], accl[g], 0, 0, 0);
        }
        __builtin_amdgcn_s_setprio(0);
    }

    // ---- cross-wave (wk) reduction of partial ctx / l through dead LDS ----
    // redA (Ks, 16KB) holds hs 0,1; redB (Vs, 16KB) holds hs 2,3.
    __syncthreads();
    float* redA = (float*)&Ks[0][0];
    float* redB = (float*)&Vs[0][0];
    if (wk == 1) {
#pragma unroll
        for (int g = 0; g < 2; ++g) {
#pragma unroll
            for (int hs = 0; hs < 4; ++hs) {
                float* dst = (hs < 2) ? redA : redB;
                int slot = ((wq * 2 + g) * 2 + (hs & 1)) * 64 + lane;
                *(floatx4*)&dst[slot * 4] = acc[g][hs];
            }
            redl[(wq * 2 + g) * 64 + lane] = accl[g][0];
        }
    }
    __syncthreads();
    if (wk == 0) {
#pragma unroll
        for (int g = 0; g < 2; ++g) {
            float lsum = accl[g][0] + redl[(wq * 2 + g) * 64 + lane];
            float inv  = 1.0f / fmaxf(lsum, 1e-30f);
            int row = qrow0 + g * 16 + l15;
#pragma unroll
            for (int hs = 0; hs < 4; ++hs) {
                const float* src = (hs < 2) ? redA : redB;
                int slot = ((wq * 2 + g) * 2 + (hs & 1)) * 64 + lane;
                floatx4 o4 = acc[g][hs] + *(const floatx4*)&src[slot * 4];
                ushort4v o;
#pragma unroll
                for (int r = 0; r < 4; ++r) o[r] = f2bf(o4[r] * inv);
                *(ushort4v*)(ctx + (size_t)(b * Sdim + row) * Ddim + h * 64 + hs * 16 + quad * 4) = o;
            }
        }
    }
}

// ---------------------------------------------------------------------------
extern "C" void kernel_launch(void* const* d_in, const int* in_sizes, int n_in,
                              void* d_out, int out_size, void* d_ws, size_t ws_size,
                              hipStream_t stream) {
    const float* x   = (const float*)d_in[0];
    const float* Wq  = (const float*)d_in[1];
    const float* bq  = (const float*)d_in[2];
    const float* Wk  = (const float*)d_in[3];
    const float* bk  = (const float*)d_in[4];
    const float* Wv  = (const float*)d_in[5];
    const float* bv  = (const float*)d_in[6];
    const float* Wo  = (const float*)d_in[7];
    const float* bo  = (const float*)d_in[8];
    // d_in[9] cross_modal_weights: softmax-shift-invariant -> unused
    const int*  mask = (const int*)d_in[10];
    // d_in[11] modality_info: unused by the reference
    float* out = (float*)d_out;

    char* ws = (char*)d_ws;
    unsigned short* xb  = (unsigned short*)(ws);                         // 8 MB
    unsigned short* Wt  = (unsigned short*)(ws + (size_t)8  * 1048576);  // 8 MB
    unsigned short* qb  = (unsigned short*)(ws + (size_t)16 * 1048576);  // 8 MB
    unsigned short* kb  = (unsigned short*)(ws + (size_t)24 * 1048576);  // 8 MB
    _Float16*       vtb = (_Float16*)     (ws + (size_t)32 * 1048576);   // 8 MB f16 [bh][hd][s]
    unsigned long long* pmk = (unsigned long long*)(ws + (size_t)40 * 1048576); // 1 MB
    unsigned short* ctxb = xb;  // alias: xb consumed before attn writes ctx

    prep_kernel<<<dim3(11264), 256, 0, stream>>>(x, Wq, Wk, Wv, Wo, mask, xb, Wt, pmk);
    qkv_mfma_kernel<<<dim3(24, 32), 256, 0, stream>>>(xb, Wt, bq, bk, bv, qb, kb, vtb);
    attn_mfma_kernel<<<dim3(512), 512, 0, stream>>>(qb, kb, vtb, pmk, ctxb);
    out_mfma_kernel<<<dim3(16, 32), 256, 0, stream>>>(ctxb, Wt, bo, out);
}